// Round 1
// 130.873 us; speedup vs baseline: 1.0329x; 1.0329x over previous
//
#include <hip/hip_runtime.h>
#include <math.h>

#define CHW  (64*16384)
#define ATT_SCALE 0.17677669529663687f  // 1/sqrt(32)

// ================= K1: a = (w1b@w1a)@x + b, per-block stats partials =================
// 512 blocks x 256 threads: block = 16 pixel-quads x 16 channel-groups (4 ch each).
__global__ __launch_bounds__(256) void k1_a_stats(
    const float* __restrict__ x, const float* __restrict__ w1a,
    const float* __restrict__ b1a, const float* __restrict__ w1b,
    const float* __restrict__ b1b, float* __restrict__ a,
    float* __restrict__ statsbuf) {
  __shared__ float sA[256];          // A1 = w1b@w1a
  __shared__ float sb1[4];
  __shared__ float pc[4][4][256];    // [comp][o][cg*16+quad]  lane-stride-1
  __shared__ float rs[64], rq[64];
  int tid = threadIdx.x;
  {
    int o = tid >> 6, c = tid & 63;
    float s = 0.f;
    #pragma unroll
    for (int k = 0; k < 4; ++k) s += w1b[o*4+k] * w1a[k*64+c];
    sA[tid] = s;
  }
  if (tid < 4) {
    float s = b1b[tid];
    #pragma unroll
    for (int k = 0; k < 4; ++k) s += w1b[tid*4+k] * b1a[k];
    sb1[tid] = s;
  }
  __syncthreads();
  int quad = tid & 15, cg = tid >> 4;
  int gq = blockIdx.x * 16 + quad;       // [0, 8192)
  int bb = gq >> 12;
  int px0 = (gq & 4095) * 4;
  const float* xp = x + bb*CHW + (cg*4)*16384 + px0;
  float4 acc[4];
  #pragma unroll
  for (int o = 0; o < 4; ++o) acc[o] = make_float4(0.f,0.f,0.f,0.f);
  #pragma unroll
  for (int cc = 0; cc < 4; ++cc) {
    float4 xv = *(const float4*)(xp + cc*16384);
    int c = cg*4 + cc;
    #pragma unroll
    for (int o = 0; o < 4; ++o) {
      float w = sA[o*64+c];
      acc[o].x += w*xv.x; acc[o].y += w*xv.y; acc[o].z += w*xv.z; acc[o].w += w*xv.w;
    }
  }
  #pragma unroll
  for (int o = 0; o < 4; ++o) {
    pc[0][o][tid] = acc[o].x; pc[1][o][tid] = acc[o].y;
    pc[2][o][tid] = acc[o].z; pc[3][o][tid] = acc[o].w;
  }
  __syncthreads();
  if (tid < 64) {
    int q2 = tid & 15, o = tid >> 4;
    float sx=0.f, sy=0.f, sz=0.f, sw=0.f;
    #pragma unroll
    for (int g2 = 0; g2 < 16; ++g2) {
      int idx = g2*16 + q2;
      sx += pc[0][o][idx]; sy += pc[1][o][idx];
      sz += pc[2][o][idx]; sw += pc[3][o][idx];
    }
    float bv = sb1[o];
    sx += bv; sy += bv; sz += bv; sw += bv;
    int gq2 = blockIdx.x*16 + q2;
    int b2 = gq2 >> 12; int p0 = (gq2 & 4095)*4;
    *(float4*)(a + b2*4*16384 + o*16384 + p0) = make_float4(sx,sy,sz,sw);
    rs[tid] = sx+sy+sz+sw;
    rq[tid] = sx*sx+sy*sy+sz*sz+sw*sw;
  }
  __syncthreads();
  for (int s2 = 32; s2; s2 >>= 1) {
    if (tid < s2) { rs[tid] += rs[tid+s2]; rq[tid] += rq[tid+s2]; }
    __syncthreads();
  }
  if (tid == 0) { statsbuf[blockIdx.x*2] = rs[0]; statsbuf[blockIdx.x*2+1] = rq[0]; }
}

// ================= K3: fused normalize+qk+attention ==================================
// 256 blocks x 512 threads. Per block: reduce stats (wave shuffle), build the group's
// 1024 key tokens (LDS) directly from 'a'; real-query blocks (qb>=4) run the 32 q-slot
// x 16-way key-split loop (queries alias the key LDS); pad-query blocks (qb<4) compute
// ONE attention row (all 128 queries of a pad block are identical) and broadcast it.
__device__ __forceinline__ float poly_exp(float d) {
  // exp(d), |d| <= 0.1768 ; deg-4 Taylor, rel err ~1.4e-6; e^c factor cancels in softmax
  return 1.f + d*(1.f + d*(0.5f + d*(0.16666667f + d*0.04166667f)));
}
__global__ __launch_bounds__(512) void k3_attn(
    const float* __restrict__ a, const float* __restrict__ statsbuf,
    const float* __restrict__ wqk, float* __restrict__ att) {
  __shared__ float4 kq[1024];         // qk of key tokens 512..1535
  __shared__ float4 kt[1024];         // normalized tok of key tokens
  __shared__ float red[16][5][128];   // [s][comp][j*32+qi]; reused as scratch by pad path
  __shared__ float sred[8];
  int tid = threadIdx.x;
  int g = blockIdx.x >> 3, qb = blockIdx.x & 7;
  int b = g >> 4, u = (g >> 2) & 3, v = g & 3;

  // ---- global stats for batch b: reduce 256 partials via wave shuffles ----
  if (tid < 256) {
    float2 p = ((const float2*)statsbuf)[b*256 + tid];
    float vs = p.x, vq = p.y;
    #pragma unroll
    for (int off = 32; off; off >>= 1) {
      vs += __shfl_down(vs, off); vq += __shfl_down(vq, off);
    }
    if ((tid & 63) == 0) { sred[tid>>6] = vs; sred[4 + (tid>>6)] = vq; }
  }
  __syncthreads();
  float mu  = (sred[0]+sred[1]+sred[2]+sred[3]) * (1.f/98304.f);
  float var = (sred[4]+sred[5]+sred[6]+sred[7]) * (1.f/98304.f) - mu*mu;
  float rsig = rsqrtf(var + 1e-5f);

  // ---- build the 1024 key tokens (tokens 512..1535; all real: Hp>=64) ----
  const float* ap = a + (b*4+u)*16384;
  for (int m = tid; m < 1024; m += 512) {
    int t = 512 + m;
    int i = t >> 5, j = m & 31;
    float4 tv = *(const float4*)(ap + (i*4 + v - 64)*128 + j*4);
    tv.x = (tv.x-mu)*rsig; tv.y = (tv.y-mu)*rsig;
    tv.z = (tv.z-mu)*rsig; tv.w = (tv.w-mu)*rsig;
    float q0 = tv.x*wqk[0] + tv.y*wqk[4] + tv.z*wqk[8]  + tv.w*wqk[12];
    float q1 = tv.x*wqk[1] + tv.y*wqk[5] + tv.z*wqk[9]  + tv.w*wqk[13];
    float q2 = tv.x*wqk[2] + tv.y*wqk[6] + tv.z*wqk[10] + tv.w*wqk[14];
    float q3 = tv.x*wqk[3] + tv.y*wqk[7] + tv.z*wqk[11] + tv.w*wqk[15];
    float inv = 1.f / (sqrtf(q0*q0 + q1*q1 + q2*q2 + q3*q3) + 1e-8f);
    kq[m] = make_float4(q0*inv, q1*inv, q2*inv, q3*inv);
    kt[m] = tv;
  }
  // token 0 (the shared pad token), per-thread registers
  float z = -mu*rsig;
  float4 t0tv = make_float4(z, z, z, z);
  float p0 = z*(wqk[0] + wqk[4] + wqk[8]  + wqk[12]);
  float p1 = z*(wqk[1] + wqk[5] + wqk[9]  + wqk[13]);
  float p2 = z*(wqk[2] + wqk[6] + wqk[10] + wqk[14]);
  float p3 = z*(wqk[3] + wqk[7] + wqk[11] + wqk[15]);
  float inv0 = 1.f / (sqrtf(p0*p0 + p1*p1 + p2*p2 + p3*p3) + 1e-8f);
  float4 t0qk = make_float4(p0*inv0, p1*inv0, p2*inv0, p3*inv0);
  __syncthreads();

  if (qb >= 4) {
    // ---- real queries: tokens [qb*128, qb*128+128) = keys [(qb-4)*128 ...) ----
    int qi = tid & 31, s = tid >> 5;      // s in [0,16)
    int t0 = (qb - 4)*128 + qi*4;
    float4 q[4];
    #pragma unroll
    for (int j = 0; j < 4; ++j) {
      float4 vq = kq[t0 + j];
      q[j] = make_float4(vq.x*ATT_SCALE, vq.y*ATT_SCALE, vq.z*ATT_SCALE, vq.w*ATT_SCALE);
    }
    float den[4] = {0.f,0.f,0.f,0.f};
    float4 ov[4];
    #pragma unroll
    for (int j = 0; j < 4; ++j) ov[j] = make_float4(0.f,0.f,0.f,0.f);
    if (s == 0) {  // 512 identical zero-pad keys folded into one weighted term
      #pragma unroll
      for (int j = 0; j < 4; ++j) {
        float d = q[j].x*t0qk.x + q[j].y*t0qk.y + q[j].z*t0qk.z + q[j].w*t0qk.w;
        float e = 512.f * poly_exp(d);
        den[j] += e;
        ov[j].x += e*t0tv.x; ov[j].y += e*t0tv.y; ov[j].z += e*t0tv.z; ov[j].w += e*t0tv.w;
      }
    }
    int m0 = s * 64;
    #pragma unroll 2
    for (int m = m0; m < m0 + 64; ++m) {
      float4 kk = kq[m];
      float4 tv = kt[m];
      #pragma unroll
      for (int j = 0; j < 4; ++j) {
        float d = q[j].x*kk.x + q[j].y*kk.y + q[j].z*kk.z + q[j].w*kk.w;
        float e = poly_exp(d);
        den[j] += e;
        ov[j].x += e*tv.x; ov[j].y += e*tv.y; ov[j].z += e*tv.z; ov[j].w += e*tv.w;
      }
    }
    #pragma unroll
    for (int j = 0; j < 4; ++j) {
      int key = j*32 + qi;
      red[s][0][key] = den[j];
      red[s][1][key] = ov[j].x; red[s][2][key] = ov[j].y;
      red[s][3][key] = ov[j].z; red[s][4][key] = ov[j].w;
    }
    __syncthreads();
    if (tid < 128) {
      int qi_r = tid & 31, j_r = tid >> 5;     // key' = j_r*32+qi_r = tid
      float dsum=0.f, ox=0.f, oy=0.f, oz=0.f, ow=0.f;
      #pragma unroll
      for (int ss = 0; ss < 16; ++ss) {
        dsum += red[ss][0][tid];
        ox += red[ss][1][tid]; oy += red[ss][2][tid];
        oz += red[ss][3][tid]; ow += red[ss][4][tid];
      }
      float inv = 1.f / dsum;
      int t = qb*128 + qi_r*4 + j_r;
      int i = t >> 5, j = t & 31;
      float* ap2 = att + b*4*16384 + (i*4+u)*128 + (j*4+v);
      ap2[0]     = ox*inv;
      ap2[16384] = oy*inv;
      ap2[32768] = oz*inv;
      ap2[49152] = ow*inv;
    }
  } else {
    // ---- pad queries: all 128 queries of this block are the identical pad token ----
    float4 qs = make_float4(t0qk.x*ATT_SCALE, t0qk.y*ATT_SCALE,
                            t0qk.z*ATT_SCALE, t0qk.w*ATT_SCALE);
    float den = 0.f; float4 ov = make_float4(0.f,0.f,0.f,0.f);
    #pragma unroll
    for (int mm = 0; mm < 2; ++mm) {
      int m = tid*2 + mm;
      float4 kk = kq[m];
      float4 tv = kt[m];
      float d = qs.x*kk.x + qs.y*kk.y + qs.z*kk.z + qs.w*kk.w;
      float e = poly_exp(d);
      den += e;
      ov.x += e*tv.x; ov.y += e*tv.y; ov.z += e*tv.z; ov.w += e*tv.w;
    }
    if (tid == 0) {  // folded 512 pad keys
      float d = qs.x*t0qk.x + qs.y*t0qk.y + qs.z*t0qk.z + qs.w*t0qk.w;
      float e = 512.f * poly_exp(d);
      den += e;
      ov.x += e*t0tv.x; ov.y += e*t0tv.y; ov.z += e*t0tv.z; ov.w += e*t0tv.w;
    }
    float* sc = &red[0][0][0];   // 5*512 floats of scratch (red is 10240 floats)
    sc[tid]        = den;
    sc[512 + tid]  = ov.x;
    sc[1024 + tid] = ov.y;
    sc[1536 + tid] = ov.z;
    sc[2048 + tid] = ov.w;
    __syncthreads();
    for (int s2 = 256; s2; s2 >>= 1) {
      if (tid < s2) {
        sc[tid]        += sc[tid + s2];
        sc[512 + tid]  += sc[512 + tid + s2];
        sc[1024 + tid] += sc[1024 + tid + s2];
        sc[1536 + tid] += sc[1536 + tid + s2];
        sc[2048 + tid] += sc[2048 + tid + s2];
      }
      __syncthreads();
    }
    float invd = 1.f / sc[0];
    float res0 = sc[512]*invd, res1 = sc[1024]*invd,
          res2 = sc[1536]*invd, res3 = sc[2048]*invd;
    // broadcast to the 128 query positions x 4 components of this block
    int comp = tid >> 7, tloc = tid & 127;
    int t = qb*128 + tloc;
    int i = t >> 5, j = t & 31;
    float val = (comp == 0) ? res0 : (comp == 1) ? res1 : (comp == 2) ? res2 : res3;
    att[b*4*16384 + comp*16384 + (i*4+u)*128 + (j*4+v)] = val;
  }
}

// ================= K4: y = x + (wc@w2)@att + bias (to d_out); h1 = relu(wf1@y) =======
// 256 blocks x 512 threads: 32 quads x 16 groups (4 y-ch + 1 h1-ch each).
__global__ __launch_bounds__(512) void k4_y_h1(
    const float* __restrict__ x, const float* __restrict__ att,
    const float* __restrict__ w2p, const float* __restrict__ b2p,
    const float* __restrict__ wcp, const float* __restrict__ bcp,
    const float* __restrict__ wf1, const float* __restrict__ bf1,
    float* __restrict__ yout, float* __restrict__ h1) {
  __shared__ float sWf[64][4];
  __shared__ float sbf[64];
  __shared__ float sw1[1024];
  __shared__ float sb1[16];
  __shared__ float4 satt[4][32];
  __shared__ float4 ylds[64][32];
  int tid = threadIdx.x;
  if (tid < 256) {
    int o = tid >> 2, k = tid & 3;
    float s = 0.f;
    for (int c = 0; c < 64; ++c) s += wcp[o*64+c] * w2p[c*4+k];
    sWf[o][k] = s;
  }
  if (tid < 64) {
    float s = bcp[tid];
    for (int c = 0; c < 64; ++c) s += wcp[tid*64+c] * b2p[c];
    sbf[tid] = s;
  }
  for (int i = tid; i < 1024; i += 512) sw1[i] = wf1[i];
  if (tid < 16) sb1[tid] = bf1[tid];
  int quad = tid & 31, og = tid >> 5;   // og in [0,16)
  int gq = blockIdx.x*32 + quad;
  int bb = gq >> 12; int px0 = (gq & 4095)*4;
  if (tid < 128) {
    int k = tid >> 5, q2 = tid & 31;
    int gq2 = blockIdx.x*32 + q2;
    int b2i = gq2 >> 12; int p0 = (gq2 & 4095)*4;
    satt[k][q2] = *(const float4*)(att + b2i*4*16384 + k*16384 + p0);
  }
  __syncthreads();
  float4 a0 = satt[0][quad], a1 = satt[1][quad], a2 = satt[2][quad], a3 = satt[3][quad];
  const float* xp = x + bb*CHW + px0;
  float* yp = yout + bb*CHW + px0;
  #pragma unroll
  for (int cc = 0; cc < 4; ++cc) {
    int c = og*4 + cc;
    float4 xv = *(const float4*)(xp + c*16384);
    float w0 = sWf[c][0], w1 = sWf[c][1], w2v = sWf[c][2], w3 = sWf[c][3];
    float bv = sbf[c];
    float4 yv;
    yv.x = xv.x + w0*a0.x + w1*a1.x + w2v*a2.x + w3*a3.x + bv;
    yv.y = xv.y + w0*a0.y + w1*a1.y + w2v*a2.y + w3*a3.y + bv;
    yv.z = xv.z + w0*a0.z + w1*a1.z + w2v*a2.z + w3*a3.z + bv;
    yv.w = xv.w + w0*a0.w + w1*a1.w + w2v*a2.w + w3*a3.w + bv;
    *(float4*)(yp + c*16384) = yv;
    ylds[c][quad] = yv;
  }
  __syncthreads();
  float bv = sb1[og];
  float4 acc = make_float4(bv, bv, bv, bv);
  #pragma unroll 8
  for (int c = 0; c < 64; ++c) {
    float4 yv = ylds[c][quad];
    float wa = sw1[og*64+c];
    acc.x += wa*yv.x; acc.y += wa*yv.y; acc.z += wa*yv.z; acc.w += wa*yv.w;
  }
  acc.x = fmaxf(acc.x,0.f); acc.y = fmaxf(acc.y,0.f);
  acc.z = fmaxf(acc.z,0.f); acc.w = fmaxf(acc.w,0.f);
  *(float4*)(h1 + bb*16*16384 + og*16384 + px0) = acc;
}

// ================= K6: out = y + wf3@relu(dilconv(h1)+bf2) + bf3 =====================
// 256 blocks (one output row each) x 512 threads: 128 px x 4 wave-uniform o2-groups.
__global__ __launch_bounds__(512) void k6_ff_out(
    const float* __restrict__ h1, const float* __restrict__ wf2,
    const float* __restrict__ bf2, const float* __restrict__ wf3,
    const float* __restrict__ bf3, float* yo) {
  __shared__ float sbuf[16][3][136];   // data at col+4; zero pads both sides
  __shared__ float h2buf[128][21];     // stride 21 coprime with 32 banks
  int tid = threadIdx.x;
  int bb = blockIdx.x >> 7, h = blockIdx.x & 127;
  for (int idx = tid; idx < 16*3*136; idx += 512) {
    int c = idx / (3*136);
    int r = (idx / 136) % 3;
    int col = idx % 136;
    int row = h - 5 + 2*r;
    int w = col - 4;
    float v = 0.f;
    if (row >= 0 && w >= 0 && w < 128)
      v = h1[bb*16*16384 + c*16384 + row*128 + w];
    sbuf[c][r][col] = v;
  }
  __syncthreads();
  int w = tid & 127;
  int g = __builtin_amdgcn_readfirstlane(tid >> 7);   // wave-uniform group in [0,4)
  float acc[4];
  #pragma unroll
  for (int o = 0; o < 4; ++o) acc[o] = bf2[g*4+o];
  #pragma unroll 4
  for (int c = 0; c < 16; ++c) {
    #pragma unroll
    for (int r = 0; r < 3; ++r) {
      float tm2 = sbuf[c][r][w+2];
      float t00 = sbuf[c][r][w+4];
      float tp2 = sbuf[c][r][w+6];
      #pragma unroll
      for (int o = 0; o < 4; ++o) {
        const float* wp = wf2 + (((g*4+o)*16 + c)*3 + r)*3;
        acc[o] += wp[0]*tm2 + wp[1]*t00 + wp[2]*tp2;
      }
    }
  }
  #pragma unroll
  for (int o = 0; o < 4; ++o) h2buf[w][g*4+o] = fmaxf(acc[o], 0.f);
  __syncthreads();
  float hv[16];
  #pragma unroll
  for (int k = 0; k < 16; ++k) hv[k] = h2buf[w][k];
  float* ybase = yo + bb*CHW + h*128 + w;
  #pragma unroll 4
  for (int oc = 0; oc < 16; ++oc) {
    int o = g*16 + oc;
    float sv = bf3[o] + ybase[o*16384];
    #pragma unroll
    for (int k = 0; k < 16; ++k) sv += wf3[o*16+k]*hv[k];
    ybase[o*16384] = sv;
  }
}

extern "C" void kernel_launch(void* const* d_in, const int* in_sizes, int n_in,
                              void* d_out, int out_size, void* d_ws, size_t ws_size,
                              hipStream_t stream) {
  (void)in_sizes; (void)n_in; (void)out_size; (void)ws_size;
  const float* x   = (const float*)d_in[0];
  const float* w1a = (const float*)d_in[1];
  const float* b1a = (const float*)d_in[2];
  const float* w1b = (const float*)d_in[3];
  const float* b1b = (const float*)d_in[4];
  const float* wqk = (const float*)d_in[5];
  const float* w2  = (const float*)d_in[6];
  const float* b2  = (const float*)d_in[7];
  const float* wc  = (const float*)d_in[8];
  const float* bc  = (const float*)d_in[9];
  const float* wf1 = (const float*)d_in[10];
  const float* bf1 = (const float*)d_in[11];
  const float* wf2 = (const float*)d_in[12];
  const float* bf2 = (const float*)d_in[13];
  const float* wf3 = (const float*)d_in[14];
  const float* bf3 = (const float*)d_in[15];

  float* ws = (float*)d_ws;
  float*  a_    = ws;                          // 131072 floats
  float*  stats = ws + 131072;                 // 1024
  float*  att   = ws + 525312;                 // 131072
  float*  h1    = ws + 656384;                 // 524288
  float*  y     = (float*)d_out;               // y staged in d_out; K6 finalizes in place

  k1_a_stats<<<512, 256, 0, stream>>>(x, w1a, b1a, w1b, b1b, a_, stats);
  k3_attn   <<<256, 512, 0, stream>>>(a_, stats, wqk, att);
  k4_y_h1   <<<256, 512, 0, stream>>>(x, att, w2, b2, wc, bc, wf1, bf1, y, h1);
  k6_ff_out <<<256, 512, 0, stream>>>(h1, wf2, bf2, wf3, bf3, y);
}

// Round 2
// 130.376 us; speedup vs baseline: 1.0368x; 1.0038x over previous
//
#include <hip/hip_runtime.h>
#include <math.h>

#define CHW  (64*16384)
#define ATT_SCALE 0.17677669529663687f  // 1/sqrt(32)

// ================= K1: a = (w1b@w1a)@x + b, per-block stats partials =================
// 512 blocks x 256 threads: block = 16 pixel-quads x 16 channel-groups (4 ch each).
__global__ __launch_bounds__(256) void k1_a_stats(
    const float* __restrict__ x, const float* __restrict__ w1a,
    const float* __restrict__ b1a, const float* __restrict__ w1b,
    const float* __restrict__ b1b, float* __restrict__ a,
    float* __restrict__ statsbuf) {
  __shared__ float sA[256];          // A1 = w1b@w1a
  __shared__ float sb1[4];
  __shared__ float pc[4][4][256];    // [comp][o][cg*16+quad]  lane-stride-1
  __shared__ float rs[64], rq[64];
  int tid = threadIdx.x;
  {
    int o = tid >> 6, c = tid & 63;
    float s = 0.f;
    #pragma unroll
    for (int k = 0; k < 4; ++k) s += w1b[o*4+k] * w1a[k*64+c];
    sA[tid] = s;
  }
  if (tid < 4) {
    float s = b1b[tid];
    #pragma unroll
    for (int k = 0; k < 4; ++k) s += w1b[tid*4+k] * b1a[k];
    sb1[tid] = s;
  }
  __syncthreads();
  int quad = tid & 15, cg = tid >> 4;
  int gq = blockIdx.x * 16 + quad;       // [0, 8192)
  int bb = gq >> 12;
  int px0 = (gq & 4095) * 4;
  const float* xp = x + bb*CHW + (cg*4)*16384 + px0;
  float4 acc[4];
  #pragma unroll
  for (int o = 0; o < 4; ++o) acc[o] = make_float4(0.f,0.f,0.f,0.f);
  #pragma unroll
  for (int cc = 0; cc < 4; ++cc) {
    float4 xv = *(const float4*)(xp + cc*16384);
    int c = cg*4 + cc;
    #pragma unroll
    for (int o = 0; o < 4; ++o) {
      float w = sA[o*64+c];
      acc[o].x += w*xv.x; acc[o].y += w*xv.y; acc[o].z += w*xv.z; acc[o].w += w*xv.w;
    }
  }
  #pragma unroll
  for (int o = 0; o < 4; ++o) {
    pc[0][o][tid] = acc[o].x; pc[1][o][tid] = acc[o].y;
    pc[2][o][tid] = acc[o].z; pc[3][o][tid] = acc[o].w;
  }
  __syncthreads();
  if (tid < 64) {
    int q2 = tid & 15, o = tid >> 4;
    float sx=0.f, sy=0.f, sz=0.f, sw=0.f;
    #pragma unroll
    for (int g2 = 0; g2 < 16; ++g2) {
      int idx = g2*16 + q2;
      sx += pc[0][o][idx]; sy += pc[1][o][idx];
      sz += pc[2][o][idx]; sw += pc[3][o][idx];
    }
    float bv = sb1[o];
    sx += bv; sy += bv; sz += bv; sw += bv;
    int gq2 = blockIdx.x*16 + q2;
    int b2 = gq2 >> 12; int p0 = (gq2 & 4095)*4;
    *(float4*)(a + b2*4*16384 + o*16384 + p0) = make_float4(sx,sy,sz,sw);
    rs[tid] = sx+sy+sz+sw;
    rq[tid] = sx*sx+sy*sy+sz*sz+sw*sw;
  }
  __syncthreads();
  for (int s2 = 32; s2; s2 >>= 1) {
    if (tid < s2) { rs[tid] += rs[tid+s2]; rq[tid] += rq[tid+s2]; }
    __syncthreads();
  }
  if (tid == 0) { statsbuf[blockIdx.x*2] = rs[0]; statsbuf[blockIdx.x*2+1] = rq[0]; }
}

// ================= K3: fused normalize+qk+attention ==================================
__device__ __forceinline__ float poly_exp(float d) {
  // exp(d), |d| <= 0.1768 ; deg-4 Taylor, rel err ~1.4e-6; e^c factor cancels in softmax
  return 1.f + d*(1.f + d*(0.5f + d*(0.16666667f + d*0.04166667f)));
}
__global__ __launch_bounds__(512) void k3_attn(
    const float* __restrict__ a, const float* __restrict__ statsbuf,
    const float* __restrict__ wqk, float* __restrict__ att) {
  __shared__ float4 kq[1024];         // qk of key tokens 512..1535
  __shared__ float4 kt[1024];         // normalized tok of key tokens
  __shared__ float red[16][5][128];   // [s][comp][j*32+qi]; reused as scratch by pad path
  __shared__ float sred[8];
  int tid = threadIdx.x;
  int g = blockIdx.x >> 3, qb = blockIdx.x & 7;
  int b = g >> 4, u = (g >> 2) & 3, v = g & 3;

  // ---- global stats for batch b: reduce 256 partials via wave shuffles ----
  if (tid < 256) {
    float2 p = ((const float2*)statsbuf)[b*256 + tid];
    float vs = p.x, vq = p.y;
    #pragma unroll
    for (int off = 32; off; off >>= 1) {
      vs += __shfl_down(vs, off); vq += __shfl_down(vq, off);
    }
    if ((tid & 63) == 0) { sred[tid>>6] = vs; sred[4 + (tid>>6)] = vq; }
  }
  __syncthreads();
  float mu  = (sred[0]+sred[1]+sred[2]+sred[3]) * (1.f/98304.f);
  float var = (sred[4]+sred[5]+sred[6]+sred[7]) * (1.f/98304.f) - mu*mu;
  float rsig = rsqrtf(var + 1e-5f);

  // ---- build the 1024 key tokens (tokens 512..1535; all real: Hp>=64) ----
  const float* ap = a + (b*4+u)*16384;
  for (int m = tid; m < 1024; m += 512) {
    int t = 512 + m;
    int i = t >> 5, j = m & 31;
    float4 tv = *(const float4*)(ap + (i*4 + v - 64)*128 + j*4);
    tv.x = (tv.x-mu)*rsig; tv.y = (tv.y-mu)*rsig;
    tv.z = (tv.z-mu)*rsig; tv.w = (tv.w-mu)*rsig;
    float q0 = tv.x*wqk[0] + tv.y*wqk[4] + tv.z*wqk[8]  + tv.w*wqk[12];
    float q1 = tv.x*wqk[1] + tv.y*wqk[5] + tv.z*wqk[9]  + tv.w*wqk[13];
    float q2 = tv.x*wqk[2] + tv.y*wqk[6] + tv.z*wqk[10] + tv.w*wqk[14];
    float q3 = tv.x*wqk[3] + tv.y*wqk[7] + tv.z*wqk[11] + tv.w*wqk[15];
    float inv = 1.f / (sqrtf(q0*q0 + q1*q1 + q2*q2 + q3*q3) + 1e-8f);
    kq[m] = make_float4(q0*inv, q1*inv, q2*inv, q3*inv);
    kt[m] = tv;
  }
  // token 0 (the shared pad token), per-thread registers
  float z = -mu*rsig;
  float4 t0tv = make_float4(z, z, z, z);
  float p0 = z*(wqk[0] + wqk[4] + wqk[8]  + wqk[12]);
  float p1 = z*(wqk[1] + wqk[5] + wqk[9]  + wqk[13]);
  float p2 = z*(wqk[2] + wqk[6] + wqk[10] + wqk[14]);
  float p3 = z*(wqk[3] + wqk[7] + wqk[11] + wqk[15]);
  float inv0 = 1.f / (sqrtf(p0*p0 + p1*p1 + p2*p2 + p3*p3) + 1e-8f);
  float4 t0qk = make_float4(p0*inv0, p1*inv0, p2*inv0, p3*inv0);
  __syncthreads();

  if (qb >= 4) {
    // ---- real queries: tokens [qb*128, qb*128+128) = keys [(qb-4)*128 ...) ----
    int qi = tid & 31, s = tid >> 5;      // s in [0,16)
    int t0 = (qb - 4)*128 + qi*4;
    float4 q[4];
    #pragma unroll
    for (int j = 0; j < 4; ++j) {
      float4 vq = kq[t0 + j];
      q[j] = make_float4(vq.x*ATT_SCALE, vq.y*ATT_SCALE, vq.z*ATT_SCALE, vq.w*ATT_SCALE);
    }
    float den[4] = {0.f,0.f,0.f,0.f};
    float4 ov[4];
    #pragma unroll
    for (int j = 0; j < 4; ++j) ov[j] = make_float4(0.f,0.f,0.f,0.f);
    if (s == 0) {  // 512 identical zero-pad keys folded into one weighted term
      #pragma unroll
      for (int j = 0; j < 4; ++j) {
        float d = q[j].x*t0qk.x + q[j].y*t0qk.y + q[j].z*t0qk.z + q[j].w*t0qk.w;
        float e = 512.f * poly_exp(d);
        den[j] += e;
        ov[j].x += e*t0tv.x; ov[j].y += e*t0tv.y; ov[j].z += e*t0tv.z; ov[j].w += e*t0tv.w;
      }
    }
    int m0 = s * 64;
    #pragma unroll 2
    for (int m = m0; m < m0 + 64; ++m) {
      float4 kk = kq[m];
      float4 tv = kt[m];
      #pragma unroll
      for (int j = 0; j < 4; ++j) {
        float d = q[j].x*kk.x + q[j].y*kk.y + q[j].z*kk.z + q[j].w*kk.w;
        float e = poly_exp(d);
        den[j] += e;
        ov[j].x += e*tv.x; ov[j].y += e*tv.y; ov[j].z += e*tv.z; ov[j].w += e*tv.w;
      }
    }
    #pragma unroll
    for (int j = 0; j < 4; ++j) {
      int key = j*32 + qi;
      red[s][0][key] = den[j];
      red[s][1][key] = ov[j].x; red[s][2][key] = ov[j].y;
      red[s][3][key] = ov[j].z; red[s][4][key] = ov[j].w;
    }
    __syncthreads();
    if (tid < 128) {
      int qi_r = tid & 31, j_r = tid >> 5;     // key' = j_r*32+qi_r = tid
      float dsum=0.f, ox=0.f, oy=0.f, oz=0.f, ow=0.f;
      #pragma unroll
      for (int ss = 0; ss < 16; ++ss) {
        dsum += red[ss][0][tid];
        ox += red[ss][1][tid]; oy += red[ss][2][tid];
        oz += red[ss][3][tid]; ow += red[ss][4][tid];
      }
      float inv = 1.f / dsum;
      int t = qb*128 + qi_r*4 + j_r;
      int i = t >> 5, j = t & 31;
      float* ap2 = att + b*4*16384 + (i*4+u)*128 + (j*4+v);
      ap2[0]     = ox*inv;
      ap2[16384] = oy*inv;
      ap2[32768] = oz*inv;
      ap2[49152] = ow*inv;
    }
  } else {
    // ---- pad queries: all 128 queries of this block are the identical pad token ----
    float4 qs = make_float4(t0qk.x*ATT_SCALE, t0qk.y*ATT_SCALE,
                            t0qk.z*ATT_SCALE, t0qk.w*ATT_SCALE);
    float den = 0.f; float4 ov = make_float4(0.f,0.f,0.f,0.f);
    #pragma unroll
    for (int mm = 0; mm < 2; ++mm) {
      int m = tid*2 + mm;
      float4 kk = kq[m];
      float4 tv = kt[m];
      float d = qs.x*kk.x + qs.y*kk.y + qs.z*kk.z + qs.w*kk.w;
      float e = poly_exp(d);
      den += e;
      ov.x += e*tv.x; ov.y += e*tv.y; ov.z += e*tv.z; ov.w += e*tv.w;
    }
    if (tid == 0) {  // folded 512 pad keys
      float d = qs.x*t0qk.x + qs.y*t0qk.y + qs.z*t0qk.z + qs.w*t0qk.w;
      float e = 512.f * poly_exp(d);
      den += e;
      ov.x += e*t0tv.x; ov.y += e*t0tv.y; ov.z += e*t0tv.z; ov.w += e*t0tv.w;
    }
    float* sc = &red[0][0][0];   // 5*512 floats of scratch (red is 10240 floats)
    sc[tid]        = den;
    sc[512 + tid]  = ov.x;
    sc[1024 + tid] = ov.y;
    sc[1536 + tid] = ov.z;
    sc[2048 + tid] = ov.w;
    __syncthreads();
    for (int s2 = 256; s2; s2 >>= 1) {
      if (tid < s2) {
        sc[tid]        += sc[tid + s2];
        sc[512 + tid]  += sc[512 + tid + s2];
        sc[1024 + tid] += sc[1024 + tid + s2];
        sc[1536 + tid] += sc[1536 + tid + s2];
        sc[2048 + tid] += sc[2048 + tid + s2];
      }
      __syncthreads();
    }
    float invd = 1.f / sc[0];
    float res0 = sc[512]*invd, res1 = sc[1024]*invd,
          res2 = sc[1536]*invd, res3 = sc[2048]*invd;
    // broadcast to the 128 query positions x 4 components of this block
    int comp = tid >> 7, tloc = tid & 127;
    int t = qb*128 + tloc;
    int i = t >> 5, j = t & 31;
    float val = (comp == 0) ? res0 : (comp == 1) ? res1 : (comp == 2) ? res2 : res3;
    att[b*4*16384 + comp*16384 + (i*4+u)*128 + (j*4+v)] = val;
  }
}

// ================= K46: fused y + ff, one output row per block =======================
// 256 blocks x 512 threads. Block = (batch, row h). Computes y for rows
// {h-5, h-3, h-1} (feeding h1 = relu(wf1@y) into LDS) and row h (kept in LDS),
// then the dilated conv + wf3 epilogue. No y/h1 global round-trip.
// XCD-chunked row mapping: 32 consecutive rows per XCD -> x/att reads L2-local.
__global__ __launch_bounds__(512) void k46_row(
    const float* __restrict__ x, const float* __restrict__ att,
    const float* __restrict__ w2p, const float* __restrict__ b2p,
    const float* __restrict__ wcp, const float* __restrict__ bcp,
    const float* __restrict__ wf1, const float* __restrict__ bf1,
    const float* __restrict__ wf2, const float* __restrict__ bf2,
    const float* __restrict__ wf3, const float* __restrict__ bf3,
    float* __restrict__ yo) {
  __shared__ float sWf[64][4];         // wc@w2
  __shared__ float sbf[64];            // wc@b2 + bc
  __shared__ float sw1[1024];          // wf1
  __shared__ float sb1[16];
  __shared__ float4 satt[4][32];
  __shared__ float4 ylds[64][32];      // y row staging; after loop = y at row h
  __shared__ float sbuf[16][3][136];   // h1 rows (h-5,h-3,h-1), data at col+4
  __shared__ float h2buf[128][21];     // stride 21 coprime with 32 banks
  int tid = threadIdx.x;
  // XCD-chunked bijection: xcd = blockIdx&7 gets rows [xcd*32, xcd*32+32)
  int lid = (blockIdx.x & 7) * 32 + (blockIdx.x >> 3);
  int bb = lid >> 7, h = lid & 127;

  if (tid < 256) {
    int o = tid >> 2, k = tid & 3;
    float s = 0.f;
    for (int c = 0; c < 64; ++c) s += wcp[o*64+c] * w2p[c*4+k];
    sWf[o][k] = s;
  }
  if (tid < 64) {
    float s = bcp[tid];
    for (int c = 0; c < 64; ++c) s += wcp[tid*64+c] * b2p[c];
    sbf[tid] = s;
  }
  for (int i = tid; i < 1024; i += 512) sw1[i] = wf1[i];
  if (tid < 16) sb1[tid] = bf1[tid];
  for (int idx = tid; idx < 16*3*136; idx += 512) (&sbuf[0][0][0])[idx] = 0.f;

  int quad = tid & 31, og = tid >> 5;   // og in [0,16)
  #pragma unroll 1
  for (int ri = 0; ri < 4; ++ri) {
    int row = (ri == 3) ? h : (h - 5 + 2*ri);
    bool valid = (row >= 0);
    __syncthreads();                    // prior ylds/satt readers done
    if (valid && tid < 128) {
      int k = tid >> 5, q2 = tid & 31;
      satt[k][q2] = *(const float4*)(att + bb*4*16384 + k*16384 + row*128 + q2*4);
    }
    __syncthreads();
    if (valid) {
      float4 a0 = satt[0][quad], a1 = satt[1][quad],
             a2 = satt[2][quad], a3 = satt[3][quad];
      const float* xp = x + bb*CHW + row*128 + quad*4;
      #pragma unroll
      for (int cc = 0; cc < 4; ++cc) {
        int c = og*4 + cc;
        float4 xv = *(const float4*)(xp + c*16384);
        float w0 = sWf[c][0], w1 = sWf[c][1], w2v = sWf[c][2], w3 = sWf[c][3];
        float bv = sbf[c];
        float4 yv;
        yv.x = xv.x + w0*a0.x + w1*a1.x + w2v*a2.x + w3*a3.x + bv;
        yv.y = xv.y + w0*a0.y + w1*a1.y + w2v*a2.y + w3*a3.y + bv;
        yv.z = xv.z + w0*a0.z + w1*a1.z + w2v*a2.z + w3*a3.z + bv;
        yv.w = xv.w + w0*a0.w + w1*a1.w + w2v*a2.w + w3*a3.w + bv;
        ylds[c][quad] = yv;
      }
    }
    __syncthreads();
    if (valid && ri < 3) {             // h1 = relu(wf1@y) -> sbuf
      float bv = sb1[og];
      float4 acc = make_float4(bv, bv, bv, bv);
      #pragma unroll 8
      for (int c = 0; c < 64; ++c) {
        float4 yv = ylds[c][quad];
        float wa = sw1[og*64+c];
        acc.x += wa*yv.x; acc.y += wa*yv.y; acc.z += wa*yv.z; acc.w += wa*yv.w;
      }
      int col = 4 + quad*4;
      sbuf[og][ri][col]   = fmaxf(acc.x, 0.f);
      sbuf[og][ri][col+1] = fmaxf(acc.y, 0.f);
      sbuf[og][ri][col+2] = fmaxf(acc.z, 0.f);
      sbuf[og][ri][col+3] = fmaxf(acc.w, 0.f);
    }
  }
  __syncthreads();   // sbuf complete (last writes at ri=2 precede ri=3's first sync)

  int w = tid & 127;
  int g = __builtin_amdgcn_readfirstlane(tid >> 7);   // wave-uniform group in [0,4)
  float acc[4];
  #pragma unroll
  for (int o = 0; o < 4; ++o) acc[o] = bf2[g*4+o];
  #pragma unroll 4
  for (int c = 0; c < 16; ++c) {
    #pragma unroll
    for (int r = 0; r < 3; ++r) {
      float tm2 = sbuf[c][r][w+2];
      float t00 = sbuf[c][r][w+4];
      float tp2 = sbuf[c][r][w+6];
      #pragma unroll
      for (int o = 0; o < 4; ++o) {
        const float* wp = wf2 + (((g*4+o)*16 + c)*3 + r)*3;
        acc[o] += wp[0]*tm2 + wp[1]*t00 + wp[2]*tp2;
      }
    }
  }
  #pragma unroll
  for (int o = 0; o < 4; ++o) h2buf[w][g*4+o] = fmaxf(acc[o], 0.f);
  __syncthreads();
  float hv[16];
  #pragma unroll
  for (int k = 0; k < 16; ++k) hv[k] = h2buf[w][k];
  const float* yrow = (const float*)ylds;   // flat [64][128]: y at row h
  float* ybase = yo + bb*CHW + h*128 + w;
  #pragma unroll 4
  for (int oc = 0; oc < 16; ++oc) {
    int o = g*16 + oc;
    float sv = bf3[o] + yrow[o*128 + w];
    #pragma unroll
    for (int k = 0; k < 16; ++k) sv += wf3[o*16+k]*hv[k];
    ybase[o*16384] = sv;
  }
}

extern "C" void kernel_launch(void* const* d_in, const int* in_sizes, int n_in,
                              void* d_out, int out_size, void* d_ws, size_t ws_size,
                              hipStream_t stream) {
  (void)in_sizes; (void)n_in; (void)out_size; (void)ws_size;
  const float* x   = (const float*)d_in[0];
  const float* w1a = (const float*)d_in[1];
  const float* b1a = (const float*)d_in[2];
  const float* w1b = (const float*)d_in[3];
  const float* b1b = (const float*)d_in[4];
  const float* wqk = (const float*)d_in[5];
  const float* w2  = (const float*)d_in[6];
  const float* b2  = (const float*)d_in[7];
  const float* wc  = (const float*)d_in[8];
  const float* bc  = (const float*)d_in[9];
  const float* wf1 = (const float*)d_in[10];
  const float* bf1 = (const float*)d_in[11];
  const float* wf2 = (const float*)d_in[12];
  const float* bf2 = (const float*)d_in[13];
  const float* wf3 = (const float*)d_in[14];
  const float* bf3 = (const float*)d_in[15];

  float* ws = (float*)d_ws;
  float*  a_    = ws;                          // 131072 floats
  float*  stats = ws + 131072;                 // 1024
  float*  att   = ws + 525312;                 // 131072

  k1_a_stats<<<512, 256, 0, stream>>>(x, w1a, b1a, w1b, b1b, a_, stats);
  k3_attn   <<<256, 512, 0, stream>>>(a_, stats, wqk, att);
  k46_row   <<<256, 512, 0, stream>>>(x, att, w2, b2, wc, bc, wf1, bf1,
                                      wf2, bf2, wf3, bf3, (float*)d_out);
}

// Round 3
// 126.084 us; speedup vs baseline: 1.0721x; 1.0340x over previous
//
#include <hip/hip_runtime.h>
#include <math.h>

#define CHW  (64*16384)
#define ATT_SCALE 0.17677669529663687f  // 1/sqrt(32)

// ================= K1: a = (w1b@w1a)@x + b, per-block stats partials =================
// 512 blocks x 256 threads: block = 16 pixel-quads x 16 channel-groups (4 ch each).
__global__ __launch_bounds__(256) void k1_a_stats(
    const float* __restrict__ x, const float* __restrict__ w1a,
    const float* __restrict__ b1a, const float* __restrict__ w1b,
    const float* __restrict__ b1b, float* __restrict__ a,
    float* __restrict__ statsbuf) {
  __shared__ float sA[256];          // A1 = w1b@w1a
  __shared__ float sb1[4];
  __shared__ float pc[4][4][256];    // [comp][o][cg*16+quad]  lane-stride-1
  __shared__ float rs[64], rq[64];
  int tid = threadIdx.x;
  {
    int o = tid >> 6, c = tid & 63;
    float s = 0.f;
    #pragma unroll
    for (int k = 0; k < 4; ++k) s += w1b[o*4+k] * w1a[k*64+c];
    sA[tid] = s;
  }
  if (tid < 4) {
    float s = b1b[tid];
    #pragma unroll
    for (int k = 0; k < 4; ++k) s += w1b[tid*4+k] * b1a[k];
    sb1[tid] = s;
  }
  __syncthreads();
  int quad = tid & 15, cg = tid >> 4;
  int gq = blockIdx.x * 16 + quad;       // [0, 8192)
  int bb = gq >> 12;
  int px0 = (gq & 4095) * 4;
  const float* xp = x + bb*CHW + (cg*4)*16384 + px0;
  float4 acc[4];
  #pragma unroll
  for (int o = 0; o < 4; ++o) acc[o] = make_float4(0.f,0.f,0.f,0.f);
  #pragma unroll
  for (int cc = 0; cc < 4; ++cc) {
    float4 xv = *(const float4*)(xp + cc*16384);
    int c = cg*4 + cc;
    #pragma unroll
    for (int o = 0; o < 4; ++o) {
      float w = sA[o*64+c];
      acc[o].x += w*xv.x; acc[o].y += w*xv.y; acc[o].z += w*xv.z; acc[o].w += w*xv.w;
    }
  }
  #pragma unroll
  for (int o = 0; o < 4; ++o) {
    pc[0][o][tid] = acc[o].x; pc[1][o][tid] = acc[o].y;
    pc[2][o][tid] = acc[o].z; pc[3][o][tid] = acc[o].w;
  }
  __syncthreads();
  if (tid < 64) {
    int q2 = tid & 15, o = tid >> 4;
    float sx=0.f, sy=0.f, sz=0.f, sw=0.f;
    #pragma unroll
    for (int g2 = 0; g2 < 16; ++g2) {
      int idx = g2*16 + q2;
      sx += pc[0][o][idx]; sy += pc[1][o][idx];
      sz += pc[2][o][idx]; sw += pc[3][o][idx];
    }
    float bv = sb1[o];
    sx += bv; sy += bv; sz += bv; sw += bv;
    int gq2 = blockIdx.x*16 + q2;
    int b2 = gq2 >> 12; int p0 = (gq2 & 4095)*4;
    *(float4*)(a + b2*4*16384 + o*16384 + p0) = make_float4(sx,sy,sz,sw);
    rs[tid] = sx+sy+sz+sw;
    rq[tid] = sx*sx+sy*sy+sz*sz+sw*sw;
  }
  __syncthreads();
  for (int s2 = 32; s2; s2 >>= 1) {
    if (tid < s2) { rs[tid] += rs[tid+s2]; rq[tid] += rq[tid+s2]; }
    __syncthreads();
  }
  if (tid == 0) { statsbuf[blockIdx.x*2] = rs[0]; statsbuf[blockIdx.x*2+1] = rq[0]; }
}

// ================= K3: fused normalize+qk+attention (balanced) =======================
// 256 blocks x 512 threads = 32 groups x 8 sub-blocks. Every sub-block handles 64
// real queries (key-split 32-way); sub-block 0 additionally computes the group's one
// shared pad-query row (2 keys/thread + wave-shuffle reduce) and broadcasts it to the
// 512 pad positions. All 256 CUs now carry equal load (previously 128 pad blocks
// idled half the chip during the heavy real-query tail).
__device__ __forceinline__ float poly_exp(float d) {
  // exp(d), |d| <= 0.1768 ; deg-4 Taylor, rel err ~1.4e-6; e^c factor cancels in softmax
  return 1.f + d*(1.f + d*(0.5f + d*(0.16666667f + d*0.04166667f)));
}
__global__ __launch_bounds__(512) void k3_attn(
    const float* __restrict__ a, const float* __restrict__ statsbuf,
    const float* __restrict__ wqk, float* __restrict__ att) {
  __shared__ float4 kq[1024];         // qk of key tokens 512..1535
  __shared__ float4 kt[1024];         // normalized tok of key tokens
  __shared__ float red[32][328];      // [s][c*64+key]; stride 328 (==8 mod 32): <=2-way
  __shared__ float sred[8];
  __shared__ float padred[8][5];      // per-wave pad-row partials (qb==0 only)
  int tid = threadIdx.x;
  int g = blockIdx.x >> 3, qb = blockIdx.x & 7;   // qb in [0,8): all real sub-blocks
  int b = g >> 4, u = (g >> 2) & 3, v = g & 3;

  // ---- global stats for batch b: reduce 256 partials via wave shuffles ----
  if (tid < 256) {
    float2 p = ((const float2*)statsbuf)[b*256 + tid];
    float vs = p.x, vq = p.y;
    #pragma unroll
    for (int off = 32; off; off >>= 1) {
      vs += __shfl_down(vs, off); vq += __shfl_down(vq, off);
    }
    if ((tid & 63) == 0) { sred[tid>>6] = vs; sred[4 + (tid>>6)] = vq; }
  }
  __syncthreads();
  float mu  = (sred[0]+sred[1]+sred[2]+sred[3]) * (1.f/98304.f);
  float var = (sred[4]+sred[5]+sred[6]+sred[7]) * (1.f/98304.f) - mu*mu;
  float rsig = rsqrtf(var + 1e-5f);

  // ---- build the 1024 key tokens (tokens 512..1535; all real: Hp>=64) ----
  const float* ap = a + (b*4+u)*16384;
  for (int m = tid; m < 1024; m += 512) {
    int t = 512 + m;
    int i = t >> 5, j = m & 31;
    float4 tv = *(const float4*)(ap + (i*4 + v - 64)*128 + j*4);
    tv.x = (tv.x-mu)*rsig; tv.y = (tv.y-mu)*rsig;
    tv.z = (tv.z-mu)*rsig; tv.w = (tv.w-mu)*rsig;
    float q0 = tv.x*wqk[0] + tv.y*wqk[4] + tv.z*wqk[8]  + tv.w*wqk[12];
    float q1 = tv.x*wqk[1] + tv.y*wqk[5] + tv.z*wqk[9]  + tv.w*wqk[13];
    float q2 = tv.x*wqk[2] + tv.y*wqk[6] + tv.z*wqk[10] + tv.w*wqk[14];
    float q3 = tv.x*wqk[3] + tv.y*wqk[7] + tv.z*wqk[11] + tv.w*wqk[15];
    float inv = 1.f / (sqrtf(q0*q0 + q1*q1 + q2*q2 + q3*q3) + 1e-8f);
    kq[m] = make_float4(q0*inv, q1*inv, q2*inv, q3*inv);
    kt[m] = tv;
  }
  // token 0 (the shared pad token), per-thread registers
  float z = -mu*rsig;
  float4 t0tv = make_float4(z, z, z, z);
  float p0 = z*(wqk[0] + wqk[4] + wqk[8]  + wqk[12]);
  float p1 = z*(wqk[1] + wqk[5] + wqk[9]  + wqk[13]);
  float p2 = z*(wqk[2] + wqk[6] + wqk[10] + wqk[14]);
  float p3 = z*(wqk[3] + wqk[7] + wqk[11] + wqk[15]);
  float inv0 = 1.f / (sqrtf(p0*p0 + p1*p1 + p2*p2 + p3*p3) + 1e-8f);
  float4 t0qk = make_float4(p0*inv0, p1*inv0, p2*inv0, p3*inv0);
  __syncthreads();

  // ---- real queries: 64 per block; query tokens t = 512 + qb*64 + qi*4 + j ----
  int qi = tid & 15, s = tid >> 4;      // s in [0,32): 32-way key split
  int t0k = qb*64 + qi*4;               // key-index of query (t - 512)
  float4 q[4];
  #pragma unroll
  for (int j = 0; j < 4; ++j) {
    float4 vq = kq[t0k + j];
    q[j] = make_float4(vq.x*ATT_SCALE, vq.y*ATT_SCALE, vq.z*ATT_SCALE, vq.w*ATT_SCALE);
  }
  float den[4] = {0.f,0.f,0.f,0.f};
  float4 ov[4];
  #pragma unroll
  for (int j = 0; j < 4; ++j) ov[j] = make_float4(0.f,0.f,0.f,0.f);
  if (s == 0) {  // 512 identical zero-pad keys folded into one weighted term
    #pragma unroll
    for (int j = 0; j < 4; ++j) {
      float d = q[j].x*t0qk.x + q[j].y*t0qk.y + q[j].z*t0qk.z + q[j].w*t0qk.w;
      float e = 512.f * poly_exp(d);
      den[j] += e;
      ov[j].x += e*t0tv.x; ov[j].y += e*t0tv.y; ov[j].z += e*t0tv.z; ov[j].w += e*t0tv.w;
    }
  }
  int m0 = s * 32;
  #pragma unroll 2
  for (int m = m0; m < m0 + 32; ++m) {
    float4 kk = kq[m];
    float4 tv = kt[m];
    #pragma unroll
    for (int j = 0; j < 4; ++j) {
      float d = q[j].x*kk.x + q[j].y*kk.y + q[j].z*kk.z + q[j].w*kk.w;
      float e = poly_exp(d);
      den[j] += e;
      ov[j].x += e*tv.x; ov[j].y += e*tv.y; ov[j].z += e*tv.z; ov[j].w += e*tv.w;
    }
  }
  #pragma unroll
  for (int j = 0; j < 4; ++j) {
    int key = j*16 + qi;               // in [0,64)
    red[s][0*64+key] = den[j];
    red[s][1*64+key] = ov[j].x; red[s][2*64+key] = ov[j].y;
    red[s][3*64+key] = ov[j].z; red[s][4*64+key] = ov[j].w;
  }

  // ---- pad row (sub-block 0 only): one query over all keys, 2 keys/thread ----
  if (qb == 0) {
    float4 qs = make_float4(t0qk.x*ATT_SCALE, t0qk.y*ATT_SCALE,
                            t0qk.z*ATT_SCALE, t0qk.w*ATT_SCALE);
    float pden = 0.f; float4 pov = make_float4(0.f,0.f,0.f,0.f);
    #pragma unroll
    for (int mm = 0; mm < 2; ++mm) {
      int m = tid*2 + mm;
      float4 kk = kq[m];
      float4 tv = kt[m];
      float d = qs.x*kk.x + qs.y*kk.y + qs.z*kk.z + qs.w*kk.w;
      float e = poly_exp(d);
      pden += e;
      pov.x += e*tv.x; pov.y += e*tv.y; pov.z += e*tv.z; pov.w += e*tv.w;
    }
    if (tid == 0) {  // folded 512 pad keys
      float d = qs.x*t0qk.x + qs.y*t0qk.y + qs.z*t0qk.z + qs.w*t0qk.w;
      float e = 512.f * poly_exp(d);
      pden += e;
      pov.x += e*t0tv.x; pov.y += e*t0tv.y; pov.z += e*t0tv.z; pov.w += e*t0tv.w;
    }
    #pragma unroll
    for (int off = 32; off; off >>= 1) {
      pden  += __shfl_down(pden,  off);
      pov.x += __shfl_down(pov.x, off); pov.y += __shfl_down(pov.y, off);
      pov.z += __shfl_down(pov.z, off); pov.w += __shfl_down(pov.w, off);
    }
    if ((tid & 63) == 0) {
      int wv = tid >> 6;
      padred[wv][0] = pden;
      padred[wv][1] = pov.x; padred[wv][2] = pov.y;
      padred[wv][3] = pov.z; padred[wv][4] = pov.w;
    }
  }
  __syncthreads();

  // ---- final real-query reduce: 64 threads, one query each ----
  if (tid < 64) {
    float dsum=0.f, ox=0.f, oy=0.f, oz=0.f, ow=0.f;
    #pragma unroll 8
    for (int ss = 0; ss < 32; ++ss) {
      dsum += red[ss][0*64+tid];
      ox += red[ss][1*64+tid]; oy += red[ss][2*64+tid];
      oz += red[ss][3*64+tid]; ow += red[ss][4*64+tid];
    }
    float inv = 1.f / dsum;
    int qi_r = tid & 15, j_r = tid >> 4;     // key = j_r*16+qi_r = tid
    int t = 512 + qb*64 + qi_r*4 + j_r;
    int i = t >> 5, j = t & 31;
    float* ap2 = att + b*4*16384 + (i*4+u)*128 + (j*4+v);
    ap2[0]     = ox*inv;
    ap2[16384] = oy*inv;
    ap2[32768] = oz*inv;
    ap2[49152] = ow*inv;
  }

  // ---- pad-row broadcast: 512 pad tokens x 4 comps (sub-block 0) ----
  if (qb == 0) {
    float dsum = padred[0][0]+padred[1][0]+padred[2][0]+padred[3][0]
               + padred[4][0]+padred[5][0]+padred[6][0]+padred[7][0];
    float invd = 1.f / dsum;
    float res[4];
    #pragma unroll
    for (int c = 0; c < 4; ++c)
      res[c] = (padred[0][c+1]+padred[1][c+1]+padred[2][c+1]+padred[3][c+1]
              + padred[4][c+1]+padred[5][c+1]+padred[6][c+1]+padred[7][c+1]) * invd;
    int t = tid;                        // pad tokens t in [0,512)
    int i = t >> 5, j = t & 31;
    float* ap2 = att + b*4*16384 + (i*4+u)*128 + (j*4+v);
    ap2[0]     = res[0];
    ap2[16384] = res[1];
    ap2[32768] = res[2];
    ap2[49152] = res[3];
  }
}

// ================= K46: fused y + ff, one output row per block =======================
// 256 blocks x 512 threads. Block = (batch, row h). Computes y for rows
// {h-5, h-3, h-1} (feeding h1 = relu(wf1@y) into LDS) and row h (kept in LDS),
// then the dilated conv + wf3 epilogue. No y/h1 global round-trip.
// XCD-chunked row mapping: 32 consecutive rows per XCD -> x/att reads L2-local.
__global__ __launch_bounds__(512) void k46_row(
    const float* __restrict__ x, const float* __restrict__ att,
    const float* __restrict__ w2p, const float* __restrict__ b2p,
    const float* __restrict__ wcp, const float* __restrict__ bcp,
    const float* __restrict__ wf1, const float* __restrict__ bf1,
    const float* __restrict__ wf2, const float* __restrict__ bf2,
    const float* __restrict__ wf3, const float* __restrict__ bf3,
    float* __restrict__ yo) {
  __shared__ float sWf[64][4];         // wc@w2
  __shared__ float sbf[64];            // wc@b2 + bc
  __shared__ float sw1[1024];          // wf1
  __shared__ float sb1[16];
  __shared__ float4 satt[4][32];
  __shared__ float4 ylds[64][32];      // y row staging; after loop = y at row h
  __shared__ float sbuf[16][3][136];   // h1 rows (h-5,h-3,h-1), data at col+4
  __shared__ float h2buf[128][21];     // stride 21 coprime with 32 banks
  int tid = threadIdx.x;
  // XCD-chunked bijection: xcd = blockIdx&7 gets rows [xcd*32, xcd*32+32)
  int lid = (blockIdx.x & 7) * 32 + (blockIdx.x >> 3);
  int bb = lid >> 7, h = lid & 127;

  if (tid < 256) {
    int o = tid >> 2, k = tid & 3;
    float s = 0.f;
    for (int c = 0; c < 64; ++c) s += wcp[o*64+c] * w2p[c*4+k];
    sWf[o][k] = s;
  }
  if (tid < 64) {
    float s = bcp[tid];
    for (int c = 0; c < 64; ++c) s += wcp[tid*64+c] * b2p[c];
    sbf[tid] = s;
  }
  for (int i = tid; i < 1024; i += 512) sw1[i] = wf1[i];
  if (tid < 16) sb1[tid] = bf1[tid];
  for (int idx = tid; idx < 16*3*136; idx += 512) (&sbuf[0][0][0])[idx] = 0.f;

  int quad = tid & 31, og = tid >> 5;   // og in [0,16)
  #pragma unroll 1
  for (int ri = 0; ri < 4; ++ri) {
    int row = (ri == 3) ? h : (h - 5 + 2*ri);
    bool valid = (row >= 0);
    __syncthreads();                    // prior ylds/satt readers done
    if (valid && tid < 128) {
      int k = tid >> 5, q2 = tid & 31;
      satt[k][q2] = *(const float4*)(att + bb*4*16384 + k*16384 + row*128 + q2*4);
    }
    __syncthreads();
    if (valid) {
      float4 a0 = satt[0][quad], a1 = satt[1][quad],
             a2 = satt[2][quad], a3 = satt[3][quad];
      const float* xp = x + bb*CHW + row*128 + quad*4;
      #pragma unroll
      for (int cc = 0; cc < 4; ++cc) {
        int c = og*4 + cc;
        float4 xv = *(const float4*)(xp + c*16384);
        float w0 = sWf[c][0], w1 = sWf[c][1], w2v = sWf[c][2], w3 = sWf[c][3];
        float bv = sbf[c];
        float4 yv;
        yv.x = xv.x + w0*a0.x + w1*a1.x + w2v*a2.x + w3*a3.x + bv;
        yv.y = xv.y + w0*a0.y + w1*a1.y + w2v*a2.y + w3*a3.y + bv;
        yv.z = xv.z + w0*a0.z + w1*a1.z + w2v*a2.z + w3*a3.z + bv;
        yv.w = xv.w + w0*a0.w + w1*a1.w + w2v*a2.w + w3*a3.w + bv;
        ylds[c][quad] = yv;
      }
    }
    __syncthreads();
    if (valid && ri < 3) {             // h1 = relu(wf1@y) -> sbuf
      float bv = sb1[og];
      float4 acc = make_float4(bv, bv, bv, bv);
      #pragma unroll 8
      for (int c = 0; c < 64; ++c) {
        float4 yv = ylds[c][quad];
        float wa = sw1[og*64+c];
        acc.x += wa*yv.x; acc.y += wa*yv.y; acc.z += wa*yv.z; acc.w += wa*yv.w;
      }
      int col = 4 + quad*4;
      sbuf[og][ri][col]   = fmaxf(acc.x, 0.f);
      sbuf[og][ri][col+1] = fmaxf(acc.y, 0.f);
      sbuf[og][ri][col+2] = fmaxf(acc.z, 0.f);
      sbuf[og][ri][col+3] = fmaxf(acc.w, 0.f);
    }
  }
  __syncthreads();   // sbuf complete (last writes at ri=2 precede ri=3's first sync)

  int w = tid & 127;
  int g = __builtin_amdgcn_readfirstlane(tid >> 7);   // wave-uniform group in [0,4)
  float acc[4];
  #pragma unroll
  for (int o = 0; o < 4; ++o) acc[o] = bf2[g*4+o];
  #pragma unroll 4
  for (int c = 0; c < 16; ++c) {
    #pragma unroll
    for (int r = 0; r < 3; ++r) {
      float tm2 = sbuf[c][r][w+2];
      float t00 = sbuf[c][r][w+4];
      float tp2 = sbuf[c][r][w+6];
      #pragma unroll
      for (int o = 0; o < 4; ++o) {
        const float* wp = wf2 + (((g*4+o)*16 + c)*3 + r)*3;
        acc[o] += wp[0]*tm2 + wp[1]*t00 + wp[2]*tp2;
      }
    }
  }
  #pragma unroll
  for (int o = 0; o < 4; ++o) h2buf[w][g*4+o] = fmaxf(acc[o], 0.f);
  __syncthreads();
  float hv[16];
  #pragma unroll
  for (int k = 0; k < 16; ++k) hv[k] = h2buf[w][k];
  const float* yrow = (const float*)ylds;   // flat [64][128]: y at row h
  float* ybase = yo + bb*CHW + h*128 + w;
  #pragma unroll 4
  for (int oc = 0; oc < 16; ++oc) {
    int o = g*16 + oc;
    float sv = bf3[o] + yrow[o*128 + w];
    #pragma unroll
    for (int k = 0; k < 16; ++k) sv += wf3[o*16+k]*hv[k];
    ybase[o*16384] = sv;
  }
}

extern "C" void kernel_launch(void* const* d_in, const int* in_sizes, int n_in,
                              void* d_out, int out_size, void* d_ws, size_t ws_size,
                              hipStream_t stream) {
  (void)in_sizes; (void)n_in; (void)out_size; (void)ws_size;
  const float* x   = (const float*)d_in[0];
  const float* w1a = (const float*)d_in[1];
  const float* b1a = (const float*)d_in[2];
  const float* w1b = (const float*)d_in[3];
  const float* b1b = (const float*)d_in[4];
  const float* wqk = (const float*)d_in[5];
  const float* w2  = (const float*)d_in[6];
  const float* b2  = (const float*)d_in[7];
  const float* wc  = (const float*)d_in[8];
  const float* bc  = (const float*)d_in[9];
  const float* wf1 = (const float*)d_in[10];
  const float* bf1 = (const float*)d_in[11];
  const float* wf2 = (const float*)d_in[12];
  const float* bf2 = (const float*)d_in[13];
  const float* wf3 = (const float*)d_in[14];
  const float* bf3 = (const float*)d_in[15];

  float* ws = (float*)d_ws;
  float*  a_    = ws;                          // 131072 floats
  float*  stats = ws + 131072;                 // 1024
  float*  att   = ws + 525312;                 // 131072

  k1_a_stats<<<512, 256, 0, stream>>>(x, w1a, b1a, w1b, b1b, a_, stats);
  k3_attn   <<<256, 512, 0, stream>>>(a_, stats, wqk, att);
  k46_row   <<<256, 512, 0, stream>>>(x, att, w2, b2, wc, bc, wf1, bf1,
                                      wf2, bf2, wf3, bf3, (float*)d_out);
}